// Round 1
// baseline (11.291 us; speedup 1.0000x reference)
//
#include <hip/hip_runtime.h>
#include <hip/hip_bf16.h>

#define EOS_TOKEN 1
#define B 8
#define T 1024
#define V 32000

// One block per sequence. 1024 threads: thread t handles position t.
__global__ void seq_nll_per_seq_kernel(const float* __restrict__ inp,
                                       const int* __restrict__ tgt,
                                       float* __restrict__ per_seq) {
    const int b = blockIdx.x;
    const int t = threadIdx.x;

    __shared__ int s_eos;
    if (t == 0) s_eos = T;  // sentinel; setup guarantees one EOS in [T/2, T)
    __syncthreads();

    const int tg = tgt[b * T + t];
    if (tg == EOS_TOKEN) atomicMin(&s_eos, t);
    __syncthreads();

    const int eos_idx = s_eos;

    float val = 0.0f;
    if (t <= eos_idx) {
        // gather: -log p[b, t, target[b,t]]
        val = -inp[(size_t)b * T * V + (size_t)t * V + (size_t)tg];
    }

    // wave (64-lane) shuffle reduction
    #pragma unroll
    for (int off = 32; off > 0; off >>= 1) {
        val += __shfl_down(val, off);
    }

    __shared__ float s_wsum[16];  // 1024 threads / 64 lanes = 16 waves
    const int wave = t >> 6;
    const int lane = t & 63;
    if (lane == 0) s_wsum[wave] = val;
    __syncthreads();

    if (t == 0) {
        float s = 0.0f;
        #pragma unroll
        for (int w = 0; w < 16; ++w) s += s_wsum[w];
        // reference divides by eos_idx (NOT eos_idx+1), as float32
        per_seq[b] = s / (float)eos_idx;
    }
}

__global__ void seq_nll_finalize_kernel(const float* __restrict__ per_seq,
                                        float* __restrict__ out) {
    if (threadIdx.x == 0 && blockIdx.x == 0) {
        float s = 0.0f;
        #pragma unroll
        for (int b = 0; b < B; ++b) s += per_seq[b];
        out[0] = s;
    }
}

extern "C" void kernel_launch(void* const* d_in, const int* in_sizes, int n_in,
                              void* d_out, int out_size, void* d_ws, size_t ws_size,
                              hipStream_t stream) {
    const float* inp = (const float*)d_in[0];   // [B, T, V] float32 log-probs
    const int* tgt = (const int*)d_in[1];       // [B, T] int32
    float* out = (float*)d_out;                 // scalar float32
    float* per_seq = (float*)d_ws;              // 8 floats scratch

    seq_nll_per_seq_kernel<<<B, T, 0, stream>>>(inp, tgt, per_seq);
    seq_nll_finalize_kernel<<<1, 64, 0, stream>>>(per_seq, out);
}

// Round 2
// 10.363 us; speedup vs baseline: 1.0895x; 1.0895x over previous
//
#include <hip/hip_runtime.h>
#include <hip/hip_bf16.h>

#define EOS_TOKEN 1
#define B 8
#define T 1024
#define V 32000

// Single block, 1024 threads. Thread t handles position t of every sequence.
// Total loss re-associated as sum over (b,t) of mask * (-logp)/eos_idx[b],
// reduced block-wide in one pass -> one kernel launch, deterministic.
__global__ void seq_nll_fused_kernel(const float* __restrict__ inp,
                                     const int* __restrict__ tgt,
                                     float* __restrict__ out) {
    const int t = threadIdx.x;

    __shared__ int s_eos[B];
    if (t < B) s_eos[t] = T;  // sentinel; setup guarantees one EOS per row
    __syncthreads();

    // load targets for all sequences at this position; find first EOS per row
    int tg[B];
    #pragma unroll
    for (int b = 0; b < B; ++b) {
        tg[b] = tgt[b * T + t];
        if (tg[b] == EOS_TOKEN) atomicMin(&s_eos[b], t);
    }
    __syncthreads();

    // gather + scale; 8 independent loads per thread for latency hiding
    float acc = 0.0f;
    #pragma unroll
    for (int b = 0; b < B; ++b) {
        const int eos = s_eos[b];
        if (t <= eos) {
            const float v = inp[(size_t)b * T * V + (size_t)t * V + (size_t)tg[b]];
            acc += -v / (float)eos;   // reference divides by eos_idx (not +1)
        }
    }

    // wave (64-lane) shuffle reduction
    #pragma unroll
    for (int off = 32; off > 0; off >>= 1) {
        acc += __shfl_down(acc, off);
    }

    __shared__ float s_wsum[16];  // 1024 / 64 = 16 waves
    const int wave = t >> 6;
    const int lane = t & 63;
    if (lane == 0) s_wsum[wave] = acc;
    __syncthreads();

    if (t == 0) {
        float s = 0.0f;
        #pragma unroll
        for (int w = 0; w < 16; ++w) s += s_wsum[w];
        out[0] = s;
    }
}

extern "C" void kernel_launch(void* const* d_in, const int* in_sizes, int n_in,
                              void* d_out, int out_size, void* d_ws, size_t ws_size,
                              hipStream_t stream) {
    const float* inp = (const float*)d_in[0];   // [B, T, V] float32 log-probs
    const int* tgt = (const int*)d_in[1];       // [B, T] int32
    float* out = (float*)d_out;                 // scalar float32

    seq_nll_fused_kernel<<<1, T, 0, stream>>>(inp, tgt, out);
}